// Round 1
// baseline (487.085 us; speedup 1.0000x reference)
//
#include <hip/hip_runtime.h>

#define N_  32
#define C_  64
#define K_  64
#define H_  128
#define W_  128
#define KB  16     // output channels per block
#define TH  4      // output rows per block
#define LDS_W 130  // W + 2 halo
#define LDS_H 6    // TH + 2 halo

__global__ __launch_bounds__(256) void conv3x3_kernel(
    const float* __restrict__ x,
    const float* __restrict__ wgt,
    const float* __restrict__ bias,
    float* __restrict__ out)
{
    __shared__ float xs[LDS_H * LDS_W];

    const int tid = threadIdx.x;
    const int tx  = tid & 127;        // w coordinate
    const int ty  = tid >> 7;         // 0 or 1 -> output rows ty and ty+2
    const int h0  = blockIdx.x * TH;  // tile start row
    const int k0  = blockIdx.y * KB;
    const int n   = blockIdx.z;

    const float* xn = x + (size_t)n * C_ * H_ * W_;

    float acc0[KB], acc1[KB];
#pragma unroll
    for (int k = 0; k < KB; ++k) { acc0[k] = 0.f; acc1[k] = 0.f; }

    const int a = ty;  // first output row (tile-relative); second is a+2

    for (int c = 0; c < C_; ++c) {
        // ---- stage 6 x 130 halo'd tile of channel c into LDS ----
        const float* xc = xn + c * (H_ * W_);
        for (int idx = tid; idx < LDS_H * LDS_W; idx += 256) {
            int i  = idx / LDS_W;
            int j  = idx - i * LDS_W;
            int hh = h0 - 1 + i;
            int ww = j - 1;
            float v = 0.f;
            if ((unsigned)hh < (unsigned)H_ && (unsigned)ww < (unsigned)W_)
                v = xc[hh * W_ + ww];
            xs[idx] = v;
        }
        __syncthreads();

        // ---- registers: 5 rows x 3 cols of x around this thread's pixels ----
        float xr[5][3];
#pragma unroll
        for (int i = 0; i < 5; ++i)
#pragma unroll
            for (int j = 0; j < 3; ++j)
                xr[i][j] = xs[(a + i) * LDS_W + tx + j];

        // ---- accumulate: weights via wave-uniform index -> SGPRs ----
        const float* wc = wgt + (size_t)(k0 * C_ + c) * 9;
#pragma unroll
        for (int k = 0; k < KB; ++k) {
            const float* wk = wc + (size_t)k * (C_ * 9);
#pragma unroll
            for (int r = 0; r < 3; ++r)
#pragma unroll
                for (int s = 0; s < 3; ++s) {
                    float wv = wk[r * 3 + s];
                    acc0[k] = fmaf(xr[r][s],     wv, acc0[k]);
                    acc1[k] = fmaf(xr[r + 2][s], wv, acc1[k]);
                }
        }
        __syncthreads();
    }

    // ---- epilogue: bias + coalesced store ----
#pragma unroll
    for (int k = 0; k < KB; ++k) {
        float b = bias[k0 + k];
        float* op = out + (((size_t)n * K_ + (k0 + k)) * H_ + (h0 + a)) * W_ + tx;
        op[0]        = acc0[k] + b;
        op[2 * W_]   = acc1[k] + b;
    }
}

extern "C" void kernel_launch(void* const* d_in, const int* in_sizes, int n_in,
                              void* d_out, int out_size, void* d_ws, size_t ws_size,
                              hipStream_t stream) {
    const float* x    = (const float*)d_in[0];
    const float* wgt  = (const float*)d_in[1];
    const float* bias = (const float*)d_in[2];
    float* out        = (float*)d_out;

    dim3 grid(H_ / TH, K_ / KB, N_);  // 32 x 4 x 32
    dim3 block(256);
    conv3x3_kernel<<<grid, block, 0, stream>>>(x, wgt, bias, out);
}

// Round 2
// 184.940 us; speedup vs baseline: 2.6337x; 2.6337x over previous
//
#include <hip/hip_runtime.h>
#include <hip/hip_bf16.h>

typedef __attribute__((ext_vector_type(8))) short bf16x8;
typedef __attribute__((ext_vector_type(16))) float f32x16;
typedef __attribute__((ext_vector_type(4))) unsigned int u32x4;

#define CIN   64
#define KOUT  64
#define HH_   128
#define WW_   128
#define HW    (HH_ * WW_)      // 16384
#define LDSW  130
#define CP    40               // padded c-slot per (row,col), bf16 elems (32 data + 8 pad)
#define XROWS 4

__device__ __forceinline__ unsigned short f2bf(float f) {
    return __builtin_bit_cast(unsigned short, __float2bfloat16(f));
}

__global__ __launch_bounds__(128) void conv_mfma(
    const float* __restrict__ x, const float* __restrict__ wgt,
    const float* __restrict__ bias, float* __restrict__ out)
{
    __shared__ __align__(16) unsigned short xs[XROWS * LDSW * CP];     // 41600 B
    __shared__ __align__(16) unsigned short wb[9 * 2 * 2 * KOUT * 8];  // 36864 B

    const int tid  = threadIdx.x;
    const int lane = tid & 63;
    const int wv   = tid >> 6;        // 0..1  (output row within tile)
    const int l31  = lane & 31;
    const int hi   = lane >> 5;       // 0..1

    // bijective XCD-aware swizzle over 2048 blocks (2048 % 8 == 0)
    const int b    = blockIdx.x;
    const int work = (b & 7) * 256 + (b >> 3);
    const int ht   = work & 63;
    const int n    = work >> 6;
    const int h0   = ht * 2;

    // ---- zero the w=-1 / w=128 halo columns once (zero for every channel) ----
    if (tid < 32) {
        const int row = tid >> 3, colsel = (tid >> 2) & 1, g = tid & 3;
        const int col = colsel ? (LDSW - 1) : 0;
        u32x4 z = {0u, 0u, 0u, 0u};
        *reinterpret_cast<u32x4*>(&xs[(row * LDSW + col) * CP + g * 8]) = z;
    }

    // ---- accumulators, bias folded into init ----
    // D layout (32x32): col(N=spatial)=lane&31, row(M=kout)=(p&3)+8*(p>>2)+4*(lane>>5)
    f32x16 acc[2][4];
    #pragma unroll
    for (int mt = 0; mt < 2; ++mt) {
        #pragma unroll
        for (int p = 0; p < 16; ++p) {
            const float bv = bias[mt * 32 + (p & 3) + 8 * (p >> 2) + 4 * hi];
            #pragma unroll
            for (int nt = 0; nt < 4; ++nt) acc[mt][nt][p] = bv;
        }
    }

    const float* xb = x + (size_t)n * CIN * HW;

    #pragma unroll 1
    for (int cc = 0; cc < 2; ++cc) {
        // ---- stage x chunk: input rows h0-1..h0+2, cols 1..128, c in [cc*32, cc*32+32) ----
        // thread tid covers global col w = tid -> LDS col tid+1; 8 c-values packed per write.
        #pragma unroll
        for (int row = 0; row < XROWS; ++row) {
            const int hh = h0 - 1 + row;
            const bool ok = (hh >= 0) && (hh < HH_);
            #pragma unroll
            for (int g = 0; g < 4; ++g) {
                float f[8];
                #pragma unroll
                for (int e = 0; e < 8; ++e)
                    f[e] = ok ? xb[(size_t)(cc * 32 + g * 8 + e) * HW + hh * WW_ + tid] : 0.f;
                u32x4 u;
                #pragma unroll
                for (int q = 0; q < 4; ++q)
                    u[q] = (unsigned)f2bf(f[2 * q]) | ((unsigned)f2bf(f[2 * q + 1]) << 16);
                *reinterpret_cast<u32x4*>(&xs[(row * LDSW + (tid + 1)) * CP + g * 8]) = u;
            }
        }
        // ---- stage weights chunk into A-fragment layout: wb[tap][ks][hi][kout][8] ----
        #pragma unroll
        for (int i = 0; i < 16; ++i) {
            const int pi = tid + 128 * i;
            const int cp = pi & 31, ko = pi >> 5;
            const int c  = cc * 32 + cp;
            const float* wp = wgt + ((size_t)ko * CIN + c) * 9;
            const int ks = cp >> 4, h8 = (cp >> 3) & 1, j = cp & 7;
            #pragma unroll
            for (int tap = 0; tap < 9; ++tap)
                wb[(((tap * 2 + ks) * 2 + h8) * KOUT + ko) * 8 + j] = f2bf(wp[tap]);
        }
        __syncthreads();

        // ---- compute: 9 taps x 2 k-steps x (2 kout-tiles x 4 spatial-tiles) ----
        #pragma unroll
        for (int r = 0; r < 3; ++r) {
            #pragma unroll
            for (int s = 0; s < 3; ++s) {
                const int tap = r * 3 + s;
                #pragma unroll
                for (int ks = 0; ks < 2; ++ks) {
                    bf16x8 af[2], bfr[4];
                    #pragma unroll
                    for (int mt = 0; mt < 2; ++mt)
                        af[mt] = *reinterpret_cast<const bf16x8*>(
                            &wb[(((tap * 2 + ks) * 2 + hi) * KOUT + mt * 32 + l31) * 8]);
                    #pragma unroll
                    for (int nt = 0; nt < 4; ++nt) {
                        const int col = nt * 32 + l31 + s;
                        bfr[nt] = *reinterpret_cast<const bf16x8*>(
                            &xs[((wv + r) * LDSW + col) * CP + ks * 16 + hi * 8]);
                    }
                    #pragma unroll
                    for (int mt = 0; mt < 2; ++mt)
                        #pragma unroll
                        for (int nt = 0; nt < 4; ++nt)
                            acc[mt][nt] = __builtin_amdgcn_mfma_f32_32x32x16_bf16(
                                af[mt], bfr[nt], acc[mt][nt], 0, 0, 0);
                }
            }
        }
        __syncthreads();
    }

    // ---- epilogue: coalesced 128B-segment stores ----
    float* ob = out + (size_t)n * KOUT * HW + (size_t)(h0 + wv) * WW_;
    #pragma unroll
    for (int mt = 0; mt < 2; ++mt)
        #pragma unroll
        for (int p = 0; p < 16; ++p) {
            const int ko = mt * 32 + (p & 3) + 8 * (p >> 2) + 4 * hi;
            #pragma unroll
            for (int nt = 0; nt < 4; ++nt)
                ob[(size_t)ko * HW + nt * 32 + l31] = acc[mt][nt][p];
        }
}

extern "C" void kernel_launch(void* const* d_in, const int* in_sizes, int n_in,
                              void* d_out, int out_size, void* d_ws, size_t ws_size,
                              hipStream_t stream) {
    const float* x    = (const float*)d_in[0];
    const float* wgt  = (const float*)d_in[1];
    const float* bias = (const float*)d_in[2];
    float* out        = (float*)d_out;

    conv_mfma<<<dim3(2048), dim3(128), 0, stream>>>(x, wgt, bias, out);
}